// Round 1
// baseline (1633.672 us; speedup 1.0000x reference)
//
#include <hip/hip_runtime.h>
#include <math.h>

#define TOKENS 16384
#define HIDDEN 4096
#define NE 64
#define TPW 8            // tokens per wave
#define WPB 4            // waves per block (256 threads)
#define IDX_OFF 0
#define SC_OFF   (TOKENS * 2)                 // 32768
#define MASK_OFF (TOKENS * 4)                 // 65536
#define AUX_OFF  (MASK_OFF + TOKENS * 2 * NE) // 2162688

// Main kernel: gate GEMM + top-2 + softmaxes + mask + f_i/m_i partial sums.
// One wave = 8 tokens, lane e = expert e.
__global__ __launch_bounds__(256, 2)
void router_kernel(const float* __restrict__ x, const float* __restrict__ Wg,
                   const float* __restrict__ bg, float* __restrict__ out,
                   float* __restrict__ gf, float* __restrict__ gm)
{
    const int lane = threadIdx.x & 63;
    const int wave = threadIdx.x >> 6;
    const int wgid = blockIdx.x * WPB + wave;   // 0..2047
    const int t0   = wgid * TPW;

    __shared__ float fsh[NE], msh[NE];
    if (threadIdx.x < NE) { fsh[threadIdx.x] = 0.f; msh[threadIdx.x] = 0.f; }
    __syncthreads();

    // 4 interleaved partial accumulators per token: keeps fp32 rounding ~2e-6
    // RMS so top-2 ordering matches the numpy reference on near-tie tokens.
    float acc[TPW][4];
    #pragma unroll
    for (int t = 0; t < TPW; ++t)
        acc[t][0] = acc[t][1] = acc[t][2] = acc[t][3] = 0.f;

    const float* wp = Wg + lane;                // column e of W_gate
    #pragma unroll 2
    for (int k = 0; k < HIDDEN; k += 4) {
        const float w0 = wp[(size_t)(k + 0) * NE];
        const float w1 = wp[(size_t)(k + 1) * NE];
        const float w2 = wp[(size_t)(k + 2) * NE];
        const float w3 = wp[(size_t)(k + 3) * NE];
        #pragma unroll
        for (int t = 0; t < TPW; ++t) {
            const float4 xv =
                *reinterpret_cast<const float4*>(&x[(size_t)(t0 + t) * HIDDEN + k]);
            acc[t][0] = fmaf(xv.x, w0, acc[t][0]);
            acc[t][1] = fmaf(xv.y, w1, acc[t][1]);
            acc[t][2] = fmaf(xv.z, w2, acc[t][2]);
            acc[t][3] = fmaf(xv.w, w3, acc[t][3]);
        }
    }

    const float bias = bg[lane];
    float f_acc = 0.f, m_acc = 0.f;

    for (int t = 0; t < TPW; ++t) {
        const float v = (acc[t][0] + acc[t][1]) + (acc[t][2] + acc[t][3]) + bias;

        // top-1: lexicographic (value desc, index asc) — matches lax.top_k ties
        float v1 = v; int i1 = lane;
        #pragma unroll
        for (int off = 32; off > 0; off >>= 1) {
            const float ov = __shfl_xor(v1, off, 64);
            const int   oi = __shfl_xor(i1, off, 64);
            if (ov > v1 || (ov == v1 && oi < i1)) { v1 = ov; i1 = oi; }
        }
        // top-2: exclude winner lane, repeat
        float v2 = (lane == i1) ? -INFINITY : v; int i2 = lane;
        #pragma unroll
        for (int off = 32; off > 0; off >>= 1) {
            const float ov = __shfl_xor(v2, off, 64);
            const int   oi = __shfl_xor(i2, off, 64);
            if (ov > v2 || (ov == v2 && oi < i2)) { v2 = ov; i2 = oi; }
        }

        // full 64-way softmax for m_i
        const float e = expf(v - v1);
        float s = e;
        #pragma unroll
        for (int off = 32; off > 0; off >>= 1) s += __shfl_xor(s, off, 64);
        m_acc += e / s;
        f_acc += ((lane == i1) ? 1.f : 0.f) + ((lane == i2) ? 1.f : 0.f);

        // softmax over the selected top-2 (max already subtracted: v1)
        const float p  = expf(v2 - v1);
        const float s0 = 1.f / (1.f + p);
        const float s1 = p / (1.f + p);

        const int tok = t0 + t;
        if (lane == 0) {
            out[IDX_OFF + tok * 2 + 0] = (float)i1;
            out[IDX_OFF + tok * 2 + 1] = (float)i2;
        } else if (lane == 1) {
            out[SC_OFF + tok * 2 + 0] = s0;
            out[SC_OFF + tok * 2 + 1] = s1;
        }
        // one-hot mask rows, coalesced 256B stores
        out[MASK_OFF + (size_t)tok * 2 * NE + lane]      = (lane == i1) ? 1.f : 0.f;
        out[MASK_OFF + (size_t)tok * 2 * NE + NE + lane] = (lane == i2) ? 1.f : 0.f;
    }

    // block-level combine, then one global atomic per expert per block
    atomicAdd(&fsh[lane], f_acc);
    atomicAdd(&msh[lane], m_acc);
    __syncthreads();
    if (threadIdx.x < NE) {
        atomicAdd(&gf[threadIdx.x], fsh[threadIdx.x]);
        atomicAdd(&gm[threadIdx.x], msh[threadIdx.x]);
    }
}

// Tiny finisher: aux_loss = 0.01 * sum(f_i * m_i) / 64
__global__ void aux_kernel(const float* __restrict__ gf,
                           const float* __restrict__ gm,
                           float* __restrict__ out)
{
    const int lane = threadIdx.x;
    const float f = gf[lane] / (float)(TOKENS * 2);
    const float m = gm[lane] / (float)TOKENS;
    float p = f * m;
    #pragma unroll
    for (int off = 32; off > 0; off >>= 1) p += __shfl_xor(p, off, 64);
    if (lane == 0) out[AUX_OFF] = 0.01f * p / (float)NE;
}

extern "C" void kernel_launch(void* const* d_in, const int* in_sizes, int n_in,
                              void* d_out, int out_size, void* d_ws, size_t ws_size,
                              hipStream_t stream)
{
    const float* x  = (const float*)d_in[0];
    const float* Wg = (const float*)d_in[1];
    const float* bg = (const float*)d_in[2];
    float* out = (float*)d_out;
    float* ws  = (float*)d_ws;     // ws[0..63] = f counts, ws[64..127] = m sums

    hipMemsetAsync(d_ws, 0, 2 * NE * sizeof(float), stream);

    const int grid = TOKENS / (TPW * WPB);   // 512 blocks
    router_kernel<<<grid, WPB * 64, 0, stream>>>(x, Wg, bg, out, ws, ws + NE);
    aux_kernel<<<1, 64, 0, stream>>>(ws, ws + NE, out);
}

// Round 2
// 880.115 us; speedup vs baseline: 1.8562x; 1.8562x over previous
//
#include <hip/hip_runtime.h>
#include <math.h>

#define TOKENS 16384
#define HIDDEN 4096
#define NE 64
#define TPB 8                 // tokens per block
#define KQ (HIDDEN / 4)       // k-range per wave (split-K across 4 waves)

#define IDX_OFF 0
#define SC_OFF   (TOKENS * 2)                 // 32768
#define MASK_OFF (TOKENS * 4)                 // 65536
#define AUX_OFF  (MASK_OFF + TOKENS * 2 * NE) // 2162688

// Block = 4 waves x 64 lanes. Lane e = expert e. Wave w = K-quarter w.
// Each block: 8 tokens, full GEMM + top-2 + softmax + mask + f/m partials.
__global__ __launch_bounds__(256, 4)
void router_kernel(const float* __restrict__ x, const float* __restrict__ Wg,
                   const float* __restrict__ bg, float* __restrict__ out,
                   float* __restrict__ gf, float* __restrict__ gm)
{
    const int lane = threadIdx.x & 63;
    const int wv   = threadIdx.x >> 6;
    const int t0   = blockIdx.x * TPB;

    __shared__ float psum[4][TPB][NE];   // per-wave K-partials
    __shared__ float fsh[NE], msh[NE];
    if (threadIdx.x < NE) { fsh[threadIdx.x] = 0.f; msh[threadIdx.x] = 0.f; }

    const float* xp = x + (size_t)t0 * HIDDEN + wv * KQ;
    const float* wp = Wg + (size_t)(wv * KQ) * NE + lane;   // column e, k-quarter wv

    float acc[TPB];
    #pragma unroll
    for (int t = 0; t < TPB; ++t) acc[t] = 0.f;

    // Explicit double-buffered pipeline: batch = 8 uniform float4 x-loads +
    // 4 coalesced w-loads. Prefetch batch k+4 while FMA-ing batch k, so the
    // compiler batches 12 loads in flight instead of serializing (R1 failure:
    // 48 VGPRs, ~270 cyc per load, 6600 cyc/iter).
    float4 xa[TPB], xb[TPB];
    float  wa[4],  wb[4];

    #pragma unroll
    for (int t = 0; t < TPB; ++t)
        xa[t] = *reinterpret_cast<const float4*>(xp + (size_t)t * HIDDEN);
    #pragma unroll
    for (int j = 0; j < 4; ++j) wa[j] = wp[j * NE];

    for (int k = 0; k < KQ - 8; k += 8) {
        // prefetch k+4 into B
        #pragma unroll
        for (int t = 0; t < TPB; ++t)
            xb[t] = *reinterpret_cast<const float4*>(xp + (size_t)t * HIDDEN + (k + 4));
        #pragma unroll
        for (int j = 0; j < 4; ++j) wb[j] = wp[(k + 4 + j) * NE];
        // consume A (k)
        #pragma unroll
        for (int t = 0; t < TPB; ++t) {
            acc[t] = fmaf(xa[t].x, wa[0], acc[t]);
            acc[t] = fmaf(xa[t].y, wa[1], acc[t]);
            acc[t] = fmaf(xa[t].z, wa[2], acc[t]);
            acc[t] = fmaf(xa[t].w, wa[3], acc[t]);
        }
        // prefetch k+8 into A
        #pragma unroll
        for (int t = 0; t < TPB; ++t)
            xa[t] = *reinterpret_cast<const float4*>(xp + (size_t)t * HIDDEN + (k + 8));
        #pragma unroll
        for (int j = 0; j < 4; ++j) wa[j] = wp[(k + 8 + j) * NE];
        // consume B (k+4)
        #pragma unroll
        for (int t = 0; t < TPB; ++t) {
            acc[t] = fmaf(xb[t].x, wb[0], acc[t]);
            acc[t] = fmaf(xb[t].y, wb[1], acc[t]);
            acc[t] = fmaf(xb[t].z, wb[2], acc[t]);
            acc[t] = fmaf(xb[t].w, wb[3], acc[t]);
        }
    }
    {   // tail: A holds k=KQ-8 (loaded in last iter); do KQ-4 via B
        #pragma unroll
        for (int t = 0; t < TPB; ++t)
            xb[t] = *reinterpret_cast<const float4*>(xp + (size_t)t * HIDDEN + (KQ - 4));
        #pragma unroll
        for (int j = 0; j < 4; ++j) wb[j] = wp[(KQ - 4 + j) * NE];
        #pragma unroll
        for (int t = 0; t < TPB; ++t) {
            acc[t] = fmaf(xa[t].x, wa[0], acc[t]);
            acc[t] = fmaf(xa[t].y, wa[1], acc[t]);
            acc[t] = fmaf(xa[t].z, wa[2], acc[t]);
            acc[t] = fmaf(xa[t].w, wa[3], acc[t]);
        }
        #pragma unroll
        for (int t = 0; t < TPB; ++t) {
            acc[t] = fmaf(xb[t].x, wb[0], acc[t]);
            acc[t] = fmaf(xb[t].y, wb[1], acc[t]);
            acc[t] = fmaf(xb[t].z, wb[2], acc[t]);
            acc[t] = fmaf(xb[t].w, wb[3], acc[t]);
        }
    }

    // combine K-partials through LDS
    #pragma unroll
    for (int t = 0; t < TPB; ++t) psum[wv][t][lane] = acc[t];
    __syncthreads();

    // epilogue: wave wv handles tokens 2*wv, 2*wv+1
    const float bias = bg[lane];
    float f_acc = 0.f, m_acc = 0.f;

    #pragma unroll
    for (int tt = 0; tt < 2; ++tt) {
        const int t = wv * 2 + tt;
        const float v = (psum[0][t][lane] + psum[1][t][lane])
                      + (psum[2][t][lane] + psum[3][t][lane]) + bias;

        // top-1 (value desc, index asc — matches lax.top_k tie-break)
        float v1 = v; int i1 = lane;
        #pragma unroll
        for (int off = 32; off > 0; off >>= 1) {
            const float ov = __shfl_xor(v1, off, 64);
            const int   oi = __shfl_xor(i1, off, 64);
            if (ov > v1 || (ov == v1 && oi < i1)) { v1 = ov; i1 = oi; }
        }
        // top-2
        float v2 = (lane == i1) ? -INFINITY : v; int i2 = lane;
        #pragma unroll
        for (int off = 32; off > 0; off >>= 1) {
            const float ov = __shfl_xor(v2, off, 64);
            const int   oi = __shfl_xor(i2, off, 64);
            if (ov > v2 || (ov == v2 && oi < i2)) { v2 = ov; i2 = oi; }
        }

        // full 64-way softmax (for m_i)
        const float e = expf(v - v1);
        float s = e;
        #pragma unroll
        for (int off = 32; off > 0; off >>= 1) s += __shfl_xor(s, off, 64);
        m_acc += e / s;
        f_acc += ((lane == i1) ? 1.f : 0.f) + ((lane == i2) ? 1.f : 0.f);

        // softmax over top-2 (max = v1 already subtracted)
        const float p  = expf(v2 - v1);
        const float s0 = 1.f / (1.f + p);
        const float s1 = p / (1.f + p);

        const int tok = t0 + t;
        if (lane == 0) {
            out[IDX_OFF + tok * 2 + 0] = (float)i1;
            out[IDX_OFF + tok * 2 + 1] = (float)i2;
        } else if (lane == 1) {
            out[SC_OFF + tok * 2 + 0] = s0;
            out[SC_OFF + tok * 2 + 1] = s1;
        }
        out[MASK_OFF + (size_t)tok * 2 * NE + lane]      = (lane == i1) ? 1.f : 0.f;
        out[MASK_OFF + (size_t)tok * 2 * NE + NE + lane] = (lane == i2) ? 1.f : 0.f;
    }

    // block combine, then one global atomic per expert
    atomicAdd(&fsh[lane], f_acc);
    atomicAdd(&msh[lane], m_acc);
    __syncthreads();
    if (threadIdx.x < NE) {
        atomicAdd(&gf[threadIdx.x], fsh[threadIdx.x]);
        atomicAdd(&gm[threadIdx.x], msh[threadIdx.x]);
    }
}

// aux_loss = 0.01 * sum(f_i * m_i) / 64
__global__ void aux_kernel(const float* __restrict__ gf,
                           const float* __restrict__ gm,
                           float* __restrict__ out)
{
    const int lane = threadIdx.x;
    const float f = gf[lane] / (float)(TOKENS * 2);
    const float m = gm[lane] / (float)TOKENS;
    float p = f * m;
    #pragma unroll
    for (int off = 32; off > 0; off >>= 1) p += __shfl_xor(p, off, 64);
    if (lane == 0) out[AUX_OFF] = 0.01f * p / (float)NE;
}

extern "C" void kernel_launch(void* const* d_in, const int* in_sizes, int n_in,
                              void* d_out, int out_size, void* d_ws, size_t ws_size,
                              hipStream_t stream)
{
    const float* x  = (const float*)d_in[0];
    const float* Wg = (const float*)d_in[1];
    const float* bg = (const float*)d_in[2];
    float* out = (float*)d_out;
    float* ws  = (float*)d_ws;    // ws[0..63] = f counts, ws[64..127] = m sums

    hipMemsetAsync(d_ws, 0, 2 * NE * sizeof(float), stream);

    const int grid = TOKENS / TPB;   // 2048 blocks
    router_kernel<<<grid, 256, 0, stream>>>(x, Wg, bg, out, ws, ws + NE);
    aux_kernel<<<1, 64, 0, stream>>>(ws, ws + NE, out);
}